// Round 9
// baseline (420.804 us; speedup 1.0000x reference)
//
#include <hip/hip_runtime.h>
#include <stdint.h>

#define S_ 512
#define B_ 64
#define V_ 50000
#define E_ 300
#define H_ 256
#define C_ 5

typedef _Float16 h8_t __attribute__((ext_vector_type(8)));
typedef float f32x4 __attribute__((ext_vector_type(4)));

// tanh(x) = 1 - 2/(e^{2x}+1); e^{2x}=2^{2x*log2e}. No clamp needed:
// x->-inf: e->0 -> -1; x->+inf: e->inf, rcp(inf)=0 -> +1.
__device__ __forceinline__ float fast_tanh(float x) {
    float e = __builtin_amdgcn_exp2f(x * 2.88539008177793f);  // 2*log2(e)
    return fmaf(-2.0f, __builtin_amdgcn_rcpf(e + 1.0f), 1.0f);
}

// ---------------------------------------------------------------------------
// Kernel A: pack W_ih (H,E) f32 -> WB f16 in B-fragment order for the xw GEMM.
// ---------------------------------------------------------------------------
__global__ void wb_prep_kernel(const float* __restrict__ W_ih,
                               uint4* __restrict__ WB) {
    int g = blockIdx.x * 256 + threadIdx.x;  // 0 .. 16*10*64-1
    if (g >= 16 * 10 * 64) return;
    int l = g & 63;
    int ks = (g >> 6) % 10;
    int nt = g / 640;
    int h = nt * 16 + (l & 15);
    int e0 = ks * 32 + (l >> 4) * 8;
    h8_t v;
#pragma unroll
    for (int j = 0; j < 8; ++j) {
        int e = e0 + j;
        v[j] = (e < E_) ? (_Float16)W_ih[(size_t)h * E_ + e] : (_Float16)0.0f;
    }
    WB[g] = __builtin_bit_cast(uint4, v);
}

// ---------------------------------------------------------------------------
// Kernel B: xw[s,b,h] = sum_e emb[idx[s,b],e]*W_ih[h,e] + b_ih[h] + b_hh[h]
// MFMA version: 512 blocks x 512 threads (8 waves).
// ---------------------------------------------------------------------------
__global__ __launch_bounds__(512, 2) void xw_kernel(
    const int* __restrict__ idx, const float* __restrict__ emb,
    const uint4* __restrict__ WB, const float* __restrict__ b_ih,
    const float* __restrict__ b_hh, float* __restrict__ xw) {
    __shared__ uint4 Afrag[4 * 10 * 64];
    const int tid = threadIdx.x;
    const int w = tid >> 6;  // wave 0..7
    const int l = tid & 63;
    const int n = l & 15;
    const int hi = l >> 4;
    const int base = blockIdx.x * 64;

    for (int cc = tid; cc < 64 * 40; cc += 512) {
        int m = cc / 40;
        int c = cc - m * 40;  // chunk: e = 8c..8c+7
        int ks = c >> 2;
        int hic = c & 3;
        const float* src = emb + (size_t)idx[base + m] * E_ + 8 * c;
        h8_t v;
        if (c < 37) {
            float4 f0 = *(const float4*)src;
            float4 f1 = *(const float4*)(src + 4);
            v[0] = (_Float16)f0.x; v[1] = (_Float16)f0.y;
            v[2] = (_Float16)f0.z; v[3] = (_Float16)f0.w;
            v[4] = (_Float16)f1.x; v[5] = (_Float16)f1.y;
            v[6] = (_Float16)f1.z; v[7] = (_Float16)f1.w;
        } else if (c == 37) {
            float4 f0 = *(const float4*)src;
            v[0] = (_Float16)f0.x; v[1] = (_Float16)f0.y;
            v[2] = (_Float16)f0.z; v[3] = (_Float16)f0.w;
            v[4] = (_Float16)0.0f; v[5] = (_Float16)0.0f;
            v[6] = (_Float16)0.0f; v[7] = (_Float16)0.0f;
        } else {
            v = (h8_t)(_Float16)0.0f;
        }
        int fl = (hic << 4) | (m & 15);
        int mt = m >> 4;
        Afrag[(mt * 10 + ks) * 64 + fl] = __builtin_bit_cast(uint4, v);
    }
    __syncthreads();

    float bias0 = b_ih[w * 32 + n] + b_hh[w * 32 + n];
    float bias1 = b_ih[w * 32 + 16 + n] + b_hh[w * 32 + 16 + n];
    f32x4 c[4][2];
#pragma unroll
    for (int mt = 0; mt < 4; ++mt) {
        c[mt][0] = (f32x4)bias0;
        c[mt][1] = (f32x4)bias1;
    }

    const uint4* wb0 = WB + ((2 * w) * 10) * 64 + l;
    const uint4* wb1 = WB + ((2 * w + 1) * 10) * 64 + l;
#pragma unroll
    for (int ks = 0; ks < 10; ++ks) {
        h8_t b0 = __builtin_bit_cast(h8_t, wb0[ks * 64]);
        h8_t b1 = __builtin_bit_cast(h8_t, wb1[ks * 64]);
#pragma unroll
        for (int mt = 0; mt < 4; ++mt) {
            h8_t a = __builtin_bit_cast(h8_t, Afrag[(mt * 10 + ks) * 64 + l]);
            c[mt][0] = __builtin_amdgcn_mfma_f32_16x16x32_f16(a, b0, c[mt][0],
                                                              0, 0, 0);
            c[mt][1] = __builtin_amdgcn_mfma_f32_16x16x32_f16(a, b1, c[mt][1],
                                                              0, 0, 0);
        }
    }

#pragma unroll
    for (int mt = 0; mt < 4; ++mt)
#pragma unroll
        for (int q = 0; q < 2; ++q) {
            float* op =
                xw + (size_t)(base + mt * 16 + hi * 4) * H_ + w * 32 + q * 16 + n;
#pragma unroll
            for (int r = 0; r < 4; ++r) op[(size_t)r * H_] = c[mt][q][r];
        }
}

// ---------------------------------------------------------------------------
// Kernel C: MFMA recurrence. 4 blocks x 16 batch cols, 256 threads = 4 waves
// (1 wave/SIMD). Per step: D[256,16] = W_hh*H + xw (xw = C operand).
//
// R9: fewer-waves-more-rows (R5 concept) + R8 light-barrier discipline.
// Rationale: per-CU LDS bytes/step = waves x 8KB (every wave ingests full H
// as B regardless of rows owned). 8 waves -> 64 reads (768cyc, the R7/R8
// wall); 4 waves -> 32 reads (384cyc). R5's 1710cyc/step failure is now
// explained by its __syncthreads() vmcnt(0) drain: at 1 wave/SIMD the
// ~900cyc HBM prefetch latency had no co-wave to hide it. Light barrier
// (lgkmcnt only) lets prefetch ride across barriers (T4).
//
//   wave w owns rows 64w..64w+63 (4 M-tiles): A = 4x8 h8_t = 128 regs.
//   __launch_bounds__(256,1) -> up to 512 VGPR/wave, no spill at ~255 demand
//   (gfx950 unified VGPR/AGPR file; MFMA reads A from AGPR natively).
//
//   H in LDS in B-FRAGMENT ORDER (conflict-free both sides):
//     byte(k, col n) = (k>>5)*1024 + ((k>>3)&3)*256 + n*16 + (k&7)*2
//   read:  lane l, slice ks -> b128 at ks*1024 + 16*l  (linear: 0 conflict)
//   write: lane (hi,n), tile mt -> b64 at const + n*16 (2-way = free)
//
//   xw prefetched 2 steps ahead into a 4-slot cv rotation (slot (I+2)&3 is
//   dead for 2 full steps -> WAR-safe, ~2 steps > HBM latency).
// ---------------------------------------------------------------------------
__global__ __launch_bounds__(256, 1) void rnn_kernel(
    const float* __restrict__ xw, const float* __restrict__ W_hh,
    float* __restrict__ hsum_out) {
    const int tid = threadIdx.x;
    const int w = tid >> 6;  // wave 0..3
    const int l = tid & 63;
    const int n = l & 15;   // batch col within block / A row / B col
    const int hi = l >> 4;  // k-group
    const int bbase = blockIdx.x * 16;
    const int rowbase = w * 64;

    __shared__ __attribute__((aligned(16))) unsigned char Hl[2][8192];
    char* lds = (char*)Hl;

    // ---- A fragments: W_hh rows rowbase..rowbase+63 as f16 ----
    h8_t a[4][8];
#pragma unroll
    for (int mt = 0; mt < 4; ++mt) {
        const float* wr = W_hh + (size_t)(rowbase + mt * 16 + n) * H_;
#pragma unroll
        for (int ks = 0; ks < 8; ++ks) {
            const float* wp = wr + ks * 32 + hi * 8;
            float4 f0 = *(const float4*)wp;
            float4 f1 = *(const float4*)(wp + 4);
            h8_t v;
            v[0] = (_Float16)f0.x; v[1] = (_Float16)f0.y;
            v[2] = (_Float16)f0.z; v[3] = (_Float16)f0.w;
            v[4] = (_Float16)f1.x; v[5] = (_Float16)f1.y;
            v[6] = (_Float16)f1.z; v[7] = (_Float16)f1.w;
            a[mt][ks] = v;
        }
    }

    // H'-write byte offsets (within a buffer): rows k0..k0+3, col n
    int wboff[4];
#pragma unroll
    for (int mt = 0; mt < 4; ++mt) {
        int k0 = rowbase + mt * 16 + hi * 4;
        wboff[mt] = ((k0 >> 5) << 10) + (((k0 >> 3) & 3) << 8) + (n << 4) +
                    ((k0 & 7) << 1);
    }

    // zero H buffer 0 (8 KB = 2048 dwords)
    for (int t = tid; t < 2048; t += 256) ((unsigned int*)Hl)[t] = 0u;

    f32x4 hs[4];
#pragma unroll
    for (int mt = 0; mt < 4; ++mt) hs[mt] = (f32x4)0.0f;

    // per-lane xw element base: xw[s][bbase+n][rowbase + mt*16 + hi*4 + r]
    const float* xwl = xw + (size_t)(bbase + n) * H_ + rowbase + hi * 4;
    // 4-slot rotation of xw-as-C-operand buffers
    f32x4 cv[4][4];
#pragma unroll
    for (int mt = 0; mt < 4; ++mt) {
        cv[0][mt] = *(const f32x4*)(xwl + mt * 16);          // s = 0
        cv[1][mt] = *(const f32x4*)(xwl + 16384 + mt * 16);  // s = 1
    }
    __syncthreads();  // full barrier once (zero-init visible)

#define STEP(CUR, I, SBASE)                                                    \
    {                                                                          \
        /* prefetch s+2 into the slot dead for the next 2 steps */             \
        int sp = (SBASE) + 2;                                                  \
        if (sp > S_ - 1) sp = S_ - 1;                                          \
        _Pragma("unroll") for (int mt = 0; mt < 4; ++mt)                       \
            cv[(I + 2) & 3][mt] =                                              \
                *(const f32x4*)(xwl + (size_t)sp * 16384 + mt * 16);           \
        h8_t bf[8];                                                            \
        _Pragma("unroll") for (int ks = 0; ks < 8; ++ks)                       \
            bf[ks] = *(const h8_t*)(lds + (CUR)*8192 + ks * 1024 + l * 16);    \
        _Pragma("unroll") for (int ks = 0; ks < 8; ++ks) {                     \
            cv[I][0] = __builtin_amdgcn_mfma_f32_16x16x32_f16(                 \
                a[0][ks], bf[ks], cv[I][0], 0, 0, 0);                          \
            cv[I][1] = __builtin_amdgcn_mfma_f32_16x16x32_f16(                 \
                a[1][ks], bf[ks], cv[I][1], 0, 0, 0);                          \
            cv[I][2] = __builtin_amdgcn_mfma_f32_16x16x32_f16(                 \
                a[2][ks], bf[ks], cv[I][2], 0, 0, 0);                          \
            cv[I][3] = __builtin_amdgcn_mfma_f32_16x16x32_f16(                 \
                a[3][ks], bf[ks], cv[I][3], 0, 0, 0);                          \
        }                                                                      \
        _Pragma("unroll") for (int mt = 0; mt < 4; ++mt) {                     \
            float h0 = fast_tanh(cv[I][mt][0]);                                \
            float h1 = fast_tanh(cv[I][mt][1]);                                \
            float h2 = fast_tanh(cv[I][mt][2]);                                \
            float h3 = fast_tanh(cv[I][mt][3]);                                \
            hs[mt][0] += h0; hs[mt][1] += h1;                                  \
            hs[mt][2] += h2; hs[mt][3] += h3;                                  \
            uint2 pk;                                                          \
            pk.x = __builtin_bit_cast(unsigned int,                            \
                                      __builtin_amdgcn_cvt_pkrtz(h0, h1));     \
            pk.y = __builtin_bit_cast(unsigned int,                            \
                                      __builtin_amdgcn_cvt_pkrtz(h2, h3));     \
            *(uint2*)(lds + ((CUR) ^ 1) * 8192 + wboff[mt]) = pk;              \
        }                                                                      \
        asm volatile("s_waitcnt lgkmcnt(0)" ::: "memory");                     \
        __builtin_amdgcn_s_barrier();                                          \
    }

    for (int s = 0; s < S_; s += 4) {
        STEP(0, 0, s)
        STEP(1, 1, s + 1)
        STEP(0, 2, s + 2)
        STEP(1, 3, s + 3)
    }
#undef STEP

#pragma unroll
    for (int mt = 0; mt < 4; ++mt) {
        float4 o;
        o.x = hs[mt][0]; o.y = hs[mt][1]; o.z = hs[mt][2]; o.w = hs[mt][3];
        *(float4*)(hsum_out + (size_t)(bbase + n) * H_ + rowbase + mt * 16 +
                   hi * 4) = o;
    }
}

// ---------------------------------------------------------------------------
// Kernel D: summed logits = hsum @ W_out^T + S*b_out, then log_softmax.
// ---------------------------------------------------------------------------
__global__ void out_kernel(const float* __restrict__ hsum,
                           const float* __restrict__ W_out,
                           const float* __restrict__ b_out,
                           float* __restrict__ out) {
    int b = threadIdx.x;
    if (b >= B_) return;
    float logits[C_];
#pragma unroll
    for (int c = 0; c < C_; ++c) {
        float acc = 0.0f;
        for (int k = 0; k < H_; ++k)
            acc = fmaf(hsum[b * H_ + k], W_out[c * H_ + k], acc);
        logits[c] = acc + (float)S_ * b_out[c];
    }
    float m = logits[0];
#pragma unroll
    for (int c = 1; c < C_; ++c) m = fmaxf(m, logits[c]);
    float sum = 0.0f;
#pragma unroll
    for (int c = 0; c < C_; ++c) sum += expf(logits[c] - m);
    float lse = logf(sum);
#pragma unroll
    for (int c = 0; c < C_; ++c) out[b * C_ + c] = logits[c] - m - lse;
}

// ---------------------------------------------------------------------------
extern "C" void kernel_launch(void* const* d_in, const int* in_sizes, int n_in,
                              void* d_out, int out_size, void* d_ws,
                              size_t ws_size, hipStream_t stream) {
    const int* idx = (const int*)d_in[0];
    const float* emb = (const float*)d_in[1];
    const float* W_ih = (const float*)d_in[2];
    const float* W_hh = (const float*)d_in[3];
    const float* b_ih = (const float*)d_in[4];
    const float* b_hh = (const float*)d_in[5];
    const float* W_out = (const float*)d_in[6];
    const float* b_out = (const float*)d_in[7];
    float* out = (float*)d_out;

    float* ws = (float*)d_ws;
    uint4* WB = (uint4*)ws;                    // 16*10*64 uint4 = 160 KB
    float* xw = ws + 40960;                    // S*B*H floats
    float* hsum = xw + (size_t)S_ * B_ * H_;   // B*H floats

    hipLaunchKernelGGL(wb_prep_kernel, dim3(40), dim3(256), 0, stream, W_ih,
                       WB);
    hipLaunchKernelGGL(xw_kernel, dim3((S_ * B_) / 64), dim3(512), 0, stream,
                       idx, emb, WB, b_ih, b_hh, xw);
    hipLaunchKernelGGL(rnn_kernel, dim3(4), dim3(256), 0, stream, xw, W_hh,
                       hsum);
    hipLaunchKernelGGL(out_kernel, dim3(1), dim3(64), 0, stream, hsum, W_out,
                       b_out, out);
}

// Round 10
// 361.655 us; speedup vs baseline: 1.1635x; 1.1635x over previous
//
#include <hip/hip_runtime.h>
#include <stdint.h>

#define S_ 512
#define B_ 64
#define V_ 50000
#define E_ 300
#define H_ 256
#define C_ 5

typedef _Float16 h8_t __attribute__((ext_vector_type(8)));
typedef float f32x4 __attribute__((ext_vector_type(4)));

// tanh(x) = 1 - 2/(e^{2x}+1); e^{2x}=2^{2x*log2e}. No clamp needed:
// x->-inf: e->0 -> -1; x->+inf: e->inf, rcp(inf)=0 -> +1.
__device__ __forceinline__ float fast_tanh(float x) {
    float e = __builtin_amdgcn_exp2f(x * 2.88539008177793f);  // 2*log2(e)
    return fmaf(-2.0f, __builtin_amdgcn_rcpf(e + 1.0f), 1.0f);
}

// Consumer-side gate: spin (rare; producer runs ~9x faster than consumption)
// until all 8 producer blocks of timestep-group grp have released, then
// acquire-fence so subsequent xw loads see their data (cross-XCD: buffer_inv).
__device__ __forceinline__ void wait_group(unsigned* gcnt, int grp) {
    while (__hip_atomic_load(&gcnt[grp], __ATOMIC_RELAXED,
                             __HIP_MEMORY_SCOPE_AGENT) != 8u) {
        __builtin_amdgcn_s_sleep(16);
    }
    __builtin_amdgcn_fence(__ATOMIC_ACQUIRE, "agent");
}

// ---------------------------------------------------------------------------
// Kernel A: pack W_ih (H,E) f32 -> WB f16 in B-fragment order for the xw GEMM.
// ---------------------------------------------------------------------------
__global__ void wb_prep_kernel(const float* __restrict__ W_ih,
                               uint4* __restrict__ WB) {
    int g = blockIdx.x * 256 + threadIdx.x;  // 0 .. 16*10*64-1
    if (g >= 16 * 10 * 64) return;
    int l = g & 63;
    int ks = (g >> 6) % 10;
    int nt = g / 640;
    int h = nt * 16 + (l & 15);
    int e0 = ks * 32 + (l >> 4) * 8;
    h8_t v;
#pragma unroll
    for (int j = 0; j < 8; ++j) {
        int e = e0 + j;
        v[j] = (e < E_) ? (_Float16)W_ih[(size_t)h * E_ + e] : (_Float16)0.0f;
    }
    WB[g] = __builtin_bit_cast(uint4, v);
}

// ---------------------------------------------------------------------------
// FUSED producer-consumer kernel. Grid = 516 blocks x 512 threads.
//   blocks 0..3   : rnn consumer (R8 structure, 8 waves x 32 rows, 275us)
//   blocks 4..515 : xw producer; block 4+g computes xw for timestep s=g
//                   (rows 64g..64g+63 of the (S*B) flat space = step g, all b)
// Producer release: stores -> __syncthreads (drains vmcnt: all block stores
// complete) -> thread0 __threadfence (wbl2: flush XCD L2) -> atomicAdd gcnt.
// Consumer: checks gcnt[(s+2)>>3]==8 once per 8 steps before prefetching into
// that group (relaxed spin + acquire fence); NOT per-step -> no per-step
// vmcnt(0) drain (R8 lesson). Producer outpaces consumer ~9x, so after the
// ~5-10us group-0 fill the gate never spins.
// ---------------------------------------------------------------------------
__global__ __launch_bounds__(512, 2) void fused_kernel(
    const int* __restrict__ idx, const float* __restrict__ emb,
    const uint4* __restrict__ WB, const float* __restrict__ b_ih,
    const float* __restrict__ b_hh, float* __restrict__ xw,
    const float* __restrict__ W_hh, float* __restrict__ hsum_out,
    unsigned* __restrict__ gcnt) {
    __shared__ __attribute__((aligned(16))) unsigned char smem[40960];
    const int tid = threadIdx.x;

    if (blockIdx.x >= 4) {
        // ================= xw producer =================
        const int g = blockIdx.x - 4;
        uint4* Afrag = (uint4*)smem;  // 4*10*64 uint4 = 40 KB
        const int w = tid >> 6;
        const int l = tid & 63;
        const int n = l & 15;
        const int hi = l >> 4;
        const int base = g * 64;

        for (int cc = tid; cc < 64 * 40; cc += 512) {
            int m = cc / 40;
            int c = cc - m * 40;  // chunk: e = 8c..8c+7
            int ks = c >> 2;
            int hic = c & 3;
            const float* src = emb + (size_t)idx[base + m] * E_ + 8 * c;
            h8_t v;
            if (c < 37) {
                float4 f0 = *(const float4*)src;
                float4 f1 = *(const float4*)(src + 4);
                v[0] = (_Float16)f0.x; v[1] = (_Float16)f0.y;
                v[2] = (_Float16)f0.z; v[3] = (_Float16)f0.w;
                v[4] = (_Float16)f1.x; v[5] = (_Float16)f1.y;
                v[6] = (_Float16)f1.z; v[7] = (_Float16)f1.w;
            } else if (c == 37) {
                float4 f0 = *(const float4*)src;
                v[0] = (_Float16)f0.x; v[1] = (_Float16)f0.y;
                v[2] = (_Float16)f0.z; v[3] = (_Float16)f0.w;
                v[4] = (_Float16)0.0f; v[5] = (_Float16)0.0f;
                v[6] = (_Float16)0.0f; v[7] = (_Float16)0.0f;
            } else {
                v = (h8_t)(_Float16)0.0f;
            }
            int fl = (hic << 4) | (m & 15);
            int mt = m >> 4;
            Afrag[(mt * 10 + ks) * 64 + fl] = __builtin_bit_cast(uint4, v);
        }
        __syncthreads();

        float bias0 = b_ih[w * 32 + n] + b_hh[w * 32 + n];
        float bias1 = b_ih[w * 32 + 16 + n] + b_hh[w * 32 + 16 + n];
        f32x4 c[4][2];
#pragma unroll
        for (int mt = 0; mt < 4; ++mt) {
            c[mt][0] = (f32x4)bias0;
            c[mt][1] = (f32x4)bias1;
        }

        const uint4* wb0 = WB + ((2 * w) * 10) * 64 + l;
        const uint4* wb1 = WB + ((2 * w + 1) * 10) * 64 + l;
#pragma unroll
        for (int ks = 0; ks < 10; ++ks) {
            h8_t b0 = __builtin_bit_cast(h8_t, wb0[ks * 64]);
            h8_t b1 = __builtin_bit_cast(h8_t, wb1[ks * 64]);
#pragma unroll
            for (int mt = 0; mt < 4; ++mt) {
                h8_t a =
                    __builtin_bit_cast(h8_t, Afrag[(mt * 10 + ks) * 64 + l]);
                c[mt][0] = __builtin_amdgcn_mfma_f32_16x16x32_f16(a, b0,
                                                                  c[mt][0], 0, 0, 0);
                c[mt][1] = __builtin_amdgcn_mfma_f32_16x16x32_f16(a, b1,
                                                                  c[mt][1], 0, 0, 0);
            }
        }

#pragma unroll
        for (int mt = 0; mt < 4; ++mt)
#pragma unroll
            for (int q = 0; q < 2; ++q) {
                float* op = xw + (size_t)(base + mt * 16 + hi * 4) * H_ +
                            w * 32 + q * 16 + n;
#pragma unroll
                for (int r = 0; r < 4; ++r) op[(size_t)r * H_] = c[mt][q][r];
            }

        // release: all block stores complete -> flush L2 -> signal
        __syncthreads();
        if (tid == 0) {
            __threadfence();
            atomicAdd(&gcnt[g >> 3], 1u);
        }
        return;
    }

    // ================= rnn consumer (R8 structure) =================
    const int w = tid >> 6;  // wave 0..7
    const int l = tid & 63;
    const int n = l & 15;   // batch col within block / A row / B col
    const int hi = l >> 4;  // k-group
    const int bbase = blockIdx.x * 16;
    const int rowbase = w * 32;

    char* lds = (char*)smem;  // [2][8192] H double-buffer

    // ---- A fragments: W_hh rows rowbase..rowbase+31 as f16 ----
    h8_t a[2][8];
#pragma unroll
    for (int mt = 0; mt < 2; ++mt) {
        const float* wr = W_hh + (size_t)(rowbase + mt * 16 + n) * H_;
#pragma unroll
        for (int ks = 0; ks < 8; ++ks) {
            const float* wp = wr + ks * 32 + hi * 8;
            float4 f0 = *(const float4*)wp;
            float4 f1 = *(const float4*)(wp + 4);
            h8_t v;
            v[0] = (_Float16)f0.x; v[1] = (_Float16)f0.y;
            v[2] = (_Float16)f0.z; v[3] = (_Float16)f0.w;
            v[4] = (_Float16)f1.x; v[5] = (_Float16)f1.y;
            v[6] = (_Float16)f1.z; v[7] = (_Float16)f1.w;
            a[mt][ks] = v;
        }
    }

    // H'-write byte offsets (within a buffer): rows k0..k0+3, col n
    int wboff[2];
#pragma unroll
    for (int mt = 0; mt < 2; ++mt) {
        int k0 = rowbase + mt * 16 + hi * 4;
        wboff[mt] = ((k0 >> 5) << 10) + (((k0 >> 3) & 3) << 8) + (n << 4) +
                    ((k0 & 7) << 1);
    }

    // zero H buffer 0 (8 KB = 2048 dwords)
    for (int t = tid; t < 2048; t += 512) ((unsigned int*)lds)[t] = 0u;

    f32x4 hs[2];
    hs[0] = (f32x4)0.0f;
    hs[1] = (f32x4)0.0f;

    // gate on timestep group 0 (steps 0..7) before first xw reads
    wait_group(gcnt, 0);

    // per-lane xw element base: xw[s][bbase+n][rowbase + mt*16 + hi*4 + r]
    const float* xwl = xw + (size_t)(bbase + n) * H_ + rowbase + hi * 4;
    // 4-slot rotation of xw-as-C-operand buffers
    f32x4 cv[4][2];
    cv[0][0] = *(const f32x4*)(xwl);                  // s = 0
    cv[0][1] = *(const f32x4*)(xwl + 16);
    cv[1][0] = *(const f32x4*)(xwl + 16384);          // s = 1
    cv[1][1] = *(const f32x4*)(xwl + 16384 + 16);
    __syncthreads();  // zero-init visible

#define STEP(CUR, I, SBASE)                                                    \
    {                                                                          \
        int sp = (SBASE) + 2;                                                  \
        if ((sp & 7) == 0 && sp < S_) wait_group(gcnt, sp >> 3);               \
        if (sp > S_ - 1) sp = S_ - 1;                                          \
        cv[(I + 2) & 3][0] = *(const f32x4*)(xwl + (size_t)sp * 16384);        \
        cv[(I + 2) & 3][1] = *(const f32x4*)(xwl + (size_t)sp * 16384 + 16);   \
        h8_t bf[8];                                                            \
        _Pragma("unroll") for (int ks = 0; ks < 8; ++ks)                       \
            bf[ks] = *(const h8_t*)(lds + (CUR)*8192 + ks * 1024 + l * 16);    \
        _Pragma("unroll") for (int ks = 0; ks < 8; ++ks) {                     \
            cv[I][0] = __builtin_amdgcn_mfma_f32_16x16x32_f16(                 \
                a[0][ks], bf[ks], cv[I][0], 0, 0, 0);                          \
            cv[I][1] = __builtin_amdgcn_mfma_f32_16x16x32_f16(                 \
                a[1][ks], bf[ks], cv[I][1], 0, 0, 0);                          \
        }                                                                      \
        _Pragma("unroll") for (int mt = 0; mt < 2; ++mt) {                     \
            float h0 = fast_tanh(cv[I][mt][0]);                                \
            float h1 = fast_tanh(cv[I][mt][1]);                                \
            float h2 = fast_tanh(cv[I][mt][2]);                                \
            float h3 = fast_tanh(cv[I][mt][3]);                                \
            hs[mt][0] += h0; hs[mt][1] += h1;                                  \
            hs[mt][2] += h2; hs[mt][3] += h3;                                  \
            uint2 pk;                                                          \
            pk.x = __builtin_bit_cast(unsigned int,                            \
                                      __builtin_amdgcn_cvt_pkrtz(h0, h1));     \
            pk.y = __builtin_bit_cast(unsigned int,                            \
                                      __builtin_amdgcn_cvt_pkrtz(h2, h3));     \
            *(uint2*)(lds + ((CUR) ^ 1) * 8192 + wboff[mt]) = pk;              \
        }                                                                      \
        asm volatile("s_waitcnt lgkmcnt(0)" ::: "memory");                     \
        __builtin_amdgcn_s_barrier();                                          \
    }

    for (int s = 0; s < S_; s += 4) {
        STEP(0, 0, s)
        STEP(1, 1, s + 1)
        STEP(0, 2, s + 2)
        STEP(1, 3, s + 3)
    }
#undef STEP

#pragma unroll
    for (int mt = 0; mt < 2; ++mt) {
        float4 o;
        o.x = hs[mt][0]; o.y = hs[mt][1]; o.z = hs[mt][2]; o.w = hs[mt][3];
        *(float4*)(hsum_out + (size_t)(bbase + n) * H_ + rowbase + mt * 16 +
                   hi * 4) = o;
    }
}

// ---------------------------------------------------------------------------
// Kernel D: summed logits = hsum @ W_out^T + S*b_out, then log_softmax.
// ---------------------------------------------------------------------------
__global__ void out_kernel(const float* __restrict__ hsum,
                           const float* __restrict__ W_out,
                           const float* __restrict__ b_out,
                           float* __restrict__ out) {
    int b = threadIdx.x;
    if (b >= B_) return;
    float logits[C_];
#pragma unroll
    for (int c = 0; c < C_; ++c) {
        float acc = 0.0f;
        for (int k = 0; k < H_; ++k)
            acc = fmaf(hsum[b * H_ + k], W_out[c * H_ + k], acc);
        logits[c] = acc + (float)S_ * b_out[c];
    }
    float m = logits[0];
#pragma unroll
    for (int c = 1; c < C_; ++c) m = fmaxf(m, logits[c]);
    float sum = 0.0f;
#pragma unroll
    for (int c = 0; c < C_; ++c) sum += expf(logits[c] - m);
    float lse = logf(sum);
#pragma unroll
    for (int c = 0; c < C_; ++c) out[b * C_ + c] = logits[c] - m - lse;
}

// ---------------------------------------------------------------------------
extern "C" void kernel_launch(void* const* d_in, const int* in_sizes, int n_in,
                              void* d_out, int out_size, void* d_ws,
                              size_t ws_size, hipStream_t stream) {
    const int* idx = (const int*)d_in[0];
    const float* emb = (const float*)d_in[1];
    const float* W_ih = (const float*)d_in[2];
    const float* W_hh = (const float*)d_in[3];
    const float* b_ih = (const float*)d_in[4];
    const float* b_hh = (const float*)d_in[5];
    const float* W_out = (const float*)d_in[6];
    const float* b_out = (const float*)d_in[7];
    float* out = (float*)d_out;

    float* ws = (float*)d_ws;
    uint4* WB = (uint4*)ws;                    // 16*10*64 uint4 = 160 KB
    float* xw = ws + 40960;                    // S*B*H floats
    float* hsum = xw + (size_t)S_ * B_ * H_;   // B*H floats
    unsigned* gcnt = (unsigned*)(hsum + B_ * H_);  // 64 u32 group counters

    hipMemsetAsync(gcnt, 0, 64 * sizeof(unsigned), stream);
    hipLaunchKernelGGL(wb_prep_kernel, dim3(40), dim3(256), 0, stream, W_ih,
                       WB);
    hipLaunchKernelGGL(fused_kernel, dim3(516), dim3(512), 0, stream, idx, emb,
                       WB, b_ih, b_hh, xw, W_hh, hsum, gcnt);
    hipLaunchKernelGGL(out_kernel, dim3(1), dim3(64), 0, stream, hsum, W_out,
                       b_out, out);
}